// Round 2
// baseline (673.201 us; speedup 1.0000x reference)
//
#include <hip/hip_runtime.h>
#include <math.h>

#define CDIV(a, b) (((a) + (b) - 1) / (b))

// ---------- 3x3 stride-2 pad-1 conv + bias + relu ----------
__global__ void conv3x3_s2_relu(const float* __restrict__ in, const float* __restrict__ w,
                                const float* __restrict__ bias, float* __restrict__ out,
                                int B, int Cin, int Hin, int Cout, int Hout) {
    int t = blockIdx.x * blockDim.x + threadIdx.x;
    int total = B * Cout * Hout * Hout;
    if (t >= total) return;
    int wo = t % Hout;
    int ho = (t / Hout) % Hout;
    int co = (t / (Hout * Hout)) % Cout;
    int b  = t / (Hout * Hout * Cout);
    float acc = bias[co];
    for (int ci = 0; ci < Cin; ++ci) {
        const float* ip = in + (size_t)(b * Cin + ci) * Hin * Hin;
        const float* wp = w + (size_t)(co * Cin + ci) * 9;
        #pragma unroll
        for (int kh = 0; kh < 3; ++kh) {
            int hi = 2 * ho + kh - 1;
            if (hi < 0 || hi >= Hin) continue;
            #pragma unroll
            for (int kw = 0; kw < 3; ++kw) {
                int wi = 2 * wo + kw - 1;
                if (wi < 0 || wi >= Hin) continue;
                acc += wp[kh * 3 + kw] * ip[hi * Hin + wi];
            }
        }
    }
    out[t] = fmaxf(acc, 0.f);
}

// ---------- qkv projection; splits into q/k/v with (dim_head, heads) heads-fastest layout ----------
__global__ void qkv_proj(const float* __restrict__ z, const float* __restrict__ w,
                         const float* __restrict__ bias, float* __restrict__ q,
                         float* __restrict__ k, float* __restrict__ v,
                         int B, int C, int N, int inner, int heads, int d) {
    int t = blockIdx.x * blockDim.x + threadIdx.x;
    int total = B * N * 3 * inner;
    if (t >= total) return;
    int n  = t % N;
    int oc = (t / N) % (3 * inner);
    int b  = t / (N * 3 * inner);
    float val = bias[oc];
    const float* zp = z + (size_t)b * C * N + n;
    const float* wp = w + (size_t)oc * C;
    for (int c = 0; c < C; ++c) val += wp[c] * zp[(size_t)c * N];
    int part = oc / inner;
    int r = oc % inner;
    int hh = r % heads;   // heads fastest in channel layout
    int dd = r / heads;
    float* dst = part == 0 ? q : (part == 1 ? k : v);
    dst[((size_t)(b * heads + hh) * N + n) * d + dd] = val;
}

// ---------- attention with relative-position bias, two-pass softmax ----------
// one block per (b*heads, row-chunk). K, V, bias-table, joff staged in LDS.
template <int D>
__global__ void attn_kernel(const float* __restrict__ q, const float* __restrict__ k,
                            const float* __restrict__ v, const float* __restrict__ table,
                            float* __restrict__ o, int N, int Hg, int T, int chunks,
                            int heads, float scale) {
    extern __shared__ float smem[];
    float* ks = smem;            // N*D
    float* vs = ks + N * D;      // N*D
    float* tb = vs + N * D;      // T
    int* joff = (int*)(tb + T);  // N

    const int bh = blockIdx.x / chunks;
    const int chunk = blockIdx.x % chunks;
    const int h = bh % heads;
    const int tid = threadIdx.x;
    const int bs = blockDim.x;
    const int W2 = 2 * Hg - 1;

    const float* kg = k + (size_t)bh * N * D;
    const float* vg = v + (size_t)bh * N * D;
    for (int t = tid; t < N * D; t += bs) { ks[t] = kg[t]; vs[t] = vg[t]; }
    for (int t = tid; t < T; t += bs) tb[t] = table[t * heads + h];
    for (int j = tid; j < N; j += bs) joff[j] = (j / Hg) * W2 + (j % Hg);
    __syncthreads();

    const int rows = N / chunks;
    for (int i = chunk * rows + tid; i < (chunk + 1) * rows; i += bs) {
        float qr[D];
        const float* qg = q + ((size_t)bh * N + i) * D;
        #pragma unroll
        for (int dd = 0; dd < D; ++dd) qr[dd] = qg[dd];
        const int ibase = (i / Hg + Hg - 1) * W2 + (i % Hg + Hg - 1);

        // pass 1: row max of (q.k + bias)   (scale>0 is monotone, applied later)
        float m = -1e30f;
        for (int j = 0; j < N; ++j) {
            float s = tb[ibase - joff[j]];
            #pragma unroll
            for (int dd = 0; dd < D; ++dd) s += qr[dd] * ks[j * D + dd];
            m = fmaxf(m, s);
        }
        // pass 2: exp + weighted V accumulation
        float l = 0.f;
        float acc[D];
        #pragma unroll
        for (int dd = 0; dd < D; ++dd) acc[dd] = 0.f;
        for (int j = 0; j < N; ++j) {
            float s = tb[ibase - joff[j]];
            #pragma unroll
            for (int dd = 0; dd < D; ++dd) s += qr[dd] * ks[j * D + dd];
            float e = __expf((s - m) * scale);
            l += e;
            #pragma unroll
            for (int dd = 0; dd < D; ++dd) acc[dd] += e * vs[j * D + dd];
        }
        float inv = 1.0f / l;
        float* og = o + ((size_t)bh * N + i) * D;
        #pragma unroll
        for (int dd = 0; dd < D; ++dd) og[dd] = acc[dd] * inv;
    }
}

// ---------- output projection + bias + residual ----------
__global__ void outproj_residual(const float* __restrict__ o, const float* __restrict__ w,
                                 const float* __restrict__ bias, const float* __restrict__ zin,
                                 float* __restrict__ zout, int B, int dim, int inner, int N,
                                 int heads, int d) {
    int t = blockIdx.x * blockDim.x + threadIdx.x;
    int total = B * dim * N;
    if (t >= total) return;
    int n = t % N;
    int c = (t / N) % dim;
    int b = t / (N * dim);
    float val = bias[c] + zin[t];
    const float* wp = w + (size_t)c * inner;
    for (int r = 0; r < inner; ++r) {
        int hh = r % heads;
        int dd = r / heads;
        val += wp[r] * o[((size_t)(b * heads + hh) * N + n) * d + dd];
    }
    zout[t] = val;
}

// ---------- global average pool (8x8) + emit first output ----------
__global__ void pool_kernel(const float* __restrict__ z, float* __restrict__ pooled,
                            float* __restrict__ out) {
    int t = blockIdx.x * blockDim.x + threadIdx.x;  // B*64
    if (t >= 32 * 64) return;
    const float* zp = z + (size_t)t * 64;
    float s = 0.f;
    for (int n = 0; n < 64; ++n) s += zp[n];
    s *= (1.0f / 64.0f);
    pooled[t] = s;
    out[t] = s;
}

// ---------- classifier head ----------
__global__ void cls_kernel(const float* __restrict__ pooled, const float* __restrict__ w,
                           const float* __restrict__ bias, float* __restrict__ out) {
    int t = blockIdx.x * blockDim.x + threadIdx.x;  // B*10
    if (t >= 320) return;
    int j = t % 10;
    int b = t / 10;
    float val = bias[j];
    const float* pp = pooled + (size_t)b * 64;
    const float* wp = w + (size_t)j * 64;
    for (int c = 0; c < 64; ++c) val += wp[c] * pp[c];
    out[2048 + t] = val;
}

extern "C" void kernel_launch(void* const* d_in, const int* in_sizes, int n_in,
                              void* d_out, int out_size, void* d_ws, size_t ws_size,
                              hipStream_t stream) {
    const int B = 32, HEADS = 3, BS = 256;
    const float* x = (const float*)d_in[0];
    float* out = (float*)d_out;

    float* ws = (float*)d_ws;
    float* Z0 = ws;               // 524288 (conv out / attn residual input)
    float* Z1 = Z0 + 524288;      // 524288 (attn out / next conv in)
    float* Q  = Z1 + 524288;      // 491520
    float* K  = Q + 491520;
    float* V  = K + 491520;
    float* O  = V + 491520;
    float* P  = O + 491520;       // 2048 pooled

    // ================= layer 1: Cin=1 H64->32, dim=16, inner=15, d=5, N=1024, Hg=32 =================
    {
        const int Cin = 1, dim = 16, Hin = 64, Hout = 32, N = 1024, inner = 15, d = 5, Hg = 32;
        const int T = (2 * Hg - 1) * (2 * Hg - 1);  // 3969
        conv3x3_s2_relu<<<CDIV(B * dim * Hout * Hout, BS), BS, 0, stream>>>(
            x, (const float*)d_in[1], (const float*)d_in[2], Z0, B, Cin, Hin, dim, Hout);
        qkv_proj<<<CDIV(B * N * 3 * inner, BS), BS, 0, stream>>>(
            Z0, (const float*)d_in[3], (const float*)d_in[4], Q, K, V, B, dim, N, inner, HEADS, d);
        const int chunks = 4;
        size_t smem = (size_t)(N * d * 2 + T) * 4 + (size_t)N * 4;  // 60932 B
        attn_kernel<5><<<B * HEADS * chunks, BS, smem, stream>>>(
            Q, K, V, (const float*)d_in[7], O, N, Hg, T, chunks, HEADS, 1.0f / sqrtf(5.0f));
        outproj_residual<<<CDIV(B * dim * N, BS), BS, 0, stream>>>(
            O, (const float*)d_in[5], (const float*)d_in[6], Z0, Z1, B, dim, inner, N, HEADS, d);
    }
    // ================= layer 2: Cin=16 H32->16, dim=32, inner=30, d=10, N=256, Hg=16 =================
    {
        const int Cin = 16, dim = 32, Hin = 32, Hout = 16, N = 256, inner = 30, d = 10, Hg = 16;
        const int T = (2 * Hg - 1) * (2 * Hg - 1);  // 961
        conv3x3_s2_relu<<<CDIV(B * dim * Hout * Hout, BS), BS, 0, stream>>>(
            Z1, (const float*)d_in[8], (const float*)d_in[9], Z0, B, Cin, Hin, dim, Hout);
        qkv_proj<<<CDIV(B * N * 3 * inner, BS), BS, 0, stream>>>(
            Z0, (const float*)d_in[10], (const float*)d_in[11], Q, K, V, B, dim, N, inner, HEADS, d);
        const int chunks = 1;
        size_t smem = (size_t)(N * d * 2 + T) * 4 + (size_t)N * 4;  // 25348 B
        attn_kernel<10><<<B * HEADS * chunks, BS, smem, stream>>>(
            Q, K, V, (const float*)d_in[14], O, N, Hg, T, chunks, HEADS, 1.0f / sqrtf(10.0f));
        outproj_residual<<<CDIV(B * dim * N, BS), BS, 0, stream>>>(
            O, (const float*)d_in[12], (const float*)d_in[13], Z0, Z1, B, dim, inner, N, HEADS, d);
    }
    // ================= layer 3: Cin=32 H16->8, dim=64, inner=63, d=21, N=64, Hg=8 =================
    {
        const int Cin = 32, dim = 64, Hin = 16, Hout = 8, N = 64, inner = 63, d = 21, Hg = 8;
        const int T = (2 * Hg - 1) * (2 * Hg - 1);  // 225
        conv3x3_s2_relu<<<CDIV(B * dim * Hout * Hout, BS), BS, 0, stream>>>(
            Z1, (const float*)d_in[15], (const float*)d_in[16], Z0, B, Cin, Hin, dim, Hout);
        qkv_proj<<<CDIV(B * N * 3 * inner, BS), BS, 0, stream>>>(
            Z0, (const float*)d_in[17], (const float*)d_in[18], Q, K, V, B, dim, N, inner, HEADS, d);
        const int chunks = 1;
        size_t smem = (size_t)(N * d * 2 + T) * 4 + (size_t)N * 4;  // 11908 B
        attn_kernel<21><<<B * HEADS * chunks, BS, smem, stream>>>(
            Q, K, V, (const float*)d_in[21], O, N, Hg, T, chunks, HEADS, 1.0f / sqrtf(21.0f));
        outproj_residual<<<CDIV(B * dim * N, BS), BS, 0, stream>>>(
            O, (const float*)d_in[19], (const float*)d_in[20], Z0, Z1, B, dim, inner, N, HEADS, d);
    }
    // ---- pool + cls ----
    pool_kernel<<<CDIV(2048, BS), BS, 0, stream>>>(Z1, P, out);
    cls_kernel<<<CDIV(320, BS), BS, 0, stream>>>(P, (const float*)d_in[22], (const float*)d_in[23], out);
}

// Round 3
// 387.049 us; speedup vs baseline: 1.7393x; 1.7393x over previous
//
#include <hip/hip_runtime.h>
#include <math.h>

#define CDIV(a, b) (((a) + (b) - 1) / (b))

// ---------- 3x3 stride-2 pad-1 conv + bias + relu ----------
__global__ void conv3x3_s2_relu(const float* __restrict__ in, const float* __restrict__ w,
                                const float* __restrict__ bias, float* __restrict__ out,
                                int B, int Cin, int Hin, int Cout, int Hout) {
    int t = blockIdx.x * blockDim.x + threadIdx.x;
    int total = B * Cout * Hout * Hout;
    if (t >= total) return;
    int wo = t % Hout;
    int ho = (t / Hout) % Hout;
    int co = (t / (Hout * Hout)) % Cout;
    int b  = t / (Hout * Hout * Cout);
    float acc = bias[co];
    for (int ci = 0; ci < Cin; ++ci) {
        const float* ip = in + (size_t)(b * Cin + ci) * Hin * Hin;
        const float* wp = w + (size_t)(co * Cin + ci) * 9;
        #pragma unroll
        for (int kh = 0; kh < 3; ++kh) {
            int hi = 2 * ho + kh - 1;
            if (hi < 0 || hi >= Hin) continue;
            #pragma unroll
            for (int kw = 0; kw < 3; ++kw) {
                int wi = 2 * wo + kw - 1;
                if (wi < 0 || wi >= Hin) continue;
                acc += wp[kh * 3 + kw] * ip[hi * Hin + wi];
            }
        }
    }
    out[t] = fmaxf(acc, 0.f);
}

// ---------- qkv projection; q/k/v layout [bh][n][d], heads-fastest channel split ----------
__global__ void qkv_proj(const float* __restrict__ z, const float* __restrict__ w,
                         const float* __restrict__ bias, float* __restrict__ q,
                         float* __restrict__ k, float* __restrict__ v,
                         int B, int C, int N, int inner, int heads, int d) {
    int t = blockIdx.x * blockDim.x + threadIdx.x;
    int total = B * N * 3 * inner;
    if (t >= total) return;
    int n  = t % N;
    int oc = (t / N) % (3 * inner);
    int b  = t / (N * 3 * inner);
    float val = bias[oc];
    const float* zp = z + (size_t)b * C * N + n;
    const float* wp = w + (size_t)oc * C;
    for (int c = 0; c < C; ++c) val += wp[c] * zp[(size_t)c * N];
    int part = oc / inner;
    int r = oc % inner;
    int hh = r % heads;   // heads fastest in channel layout
    int dd = r / heads;
    float* dst = part == 0 ? q : (part == 1 ? k : v);
    dst[((size_t)(b * heads + hh) * N + n) * d + dd] = val;
}

// ---------- attention: one-pass no-max softmax, 4-wave j-split, RPT rows/thread ----------
// block = 256 threads = 4 waves. wave w handles j in [w*N/4, (w+1)*N/4).
// rows per block = 64*RPT; grid = B*heads*IC, IC = N/(64*RPT).
// O written as [bh][d][N] (coalesced).
template <int D, int RPT>
__global__ void attn2(const float* __restrict__ q, const float* __restrict__ k,
                      const float* __restrict__ v, const float* __restrict__ table,
                      float* __restrict__ o, int N, int log2Hg, int T, int IC, float scale) {
    extern __shared__ float smem[];
    const int ROWS = 64 * RPT;
    float* ks = smem;            // N*D
    float* vs = ks + N * D;      // N*D
    float* tb = vs + N * D;      // T
    float* comb = smem;          // 4*ROWS*(D+1), overlays ks/vs after j-loop

    const int heads = 3;
    const int bh = blockIdx.x / IC;
    const int chunk = blockIdx.x % IC;
    const int h = bh % heads;
    const int tid = threadIdx.x;
    const int wave = tid >> 6;
    const int lane = tid & 63;
    const int Hg = 1 << log2Hg;
    const int W2 = 2 * Hg - 1;
    const int base = chunk * ROWS;

    // load q rows (global, independent of LDS)
    float qr[RPT][D];
    int ibase[RPT];
    #pragma unroll
    for (int r = 0; r < RPT; ++r) {
        int i = base + lane + 64 * r;
        const float* qg = q + ((size_t)bh * N + i) * D;
        #pragma unroll
        for (int dd = 0; dd < D; ++dd) qr[r][dd] = qg[dd];
        ibase[r] = ((i >> log2Hg) + Hg - 1) * W2 + (i & (Hg - 1)) + Hg - 1;
    }

    // stage K/V (float4) and bias table
    {
        const float4* kg4 = (const float4*)(k + (size_t)bh * N * D);
        const float4* vg4 = (const float4*)(v + (size_t)bh * N * D);
        float4* ks4 = (float4*)ks;
        float4* vs4 = (float4*)vs;
        int nd4 = N * D / 4;
        for (int t = tid; t < nd4; t += 256) { ks4[t] = kg4[t]; vs4[t] = vg4[t]; }
        for (int t = tid; t < T; t += 256) tb[t] = table[t * heads + h];
    }
    __syncthreads();

    float acc[RPT][D];
    float lsum[RPT];
    #pragma unroll
    for (int r = 0; r < RPT; ++r) {
        lsum[r] = 0.f;
        #pragma unroll
        for (int dd = 0; dd < D; ++dd) acc[r][dd] = 0.f;
    }

    const int NJ = N >> 2;
    const int j0 = wave * NJ;
    for (int j = j0; j < j0 + NJ; ++j) {
        const int joff = (j >> log2Hg) * W2 + (j & (Hg - 1));
        float kr[D], vr[D];
        #pragma unroll
        for (int dd = 0; dd < D; ++dd) kr[dd] = ks[j * D + dd];
        #pragma unroll
        for (int dd = 0; dd < D; ++dd) vr[dd] = vs[j * D + dd];
        #pragma unroll
        for (int r = 0; r < RPT; ++r) {
            float s = tb[ibase[r] - joff];
            #pragma unroll
            for (int dd = 0; dd < D; ++dd) s += qr[r][dd] * kr[dd];
            float e = __expf(s * scale);
            lsum[r] += e;
            #pragma unroll
            for (int dd = 0; dd < D; ++dd) acc[r][dd] += e * vr[dd];
        }
    }

    // write per-wave partials (comb overlays dead ks/vs/tb)
    __syncthreads();
    #pragma unroll
    for (int r = 0; r < RPT; ++r) {
        int lr = lane + 64 * r;
        float* cp = comb + ((size_t)(wave * ROWS) + lr) * (D + 1);
        #pragma unroll
        for (int dd = 0; dd < D; ++dd) cp[dd] = acc[r][dd];
        cp[D] = lsum[r];
    }
    __syncthreads();

    // combine: thread t owns local row t
    if (tid < ROWS) {
        float af[D];
        #pragma unroll
        for (int dd = 0; dd < D; ++dd) af[dd] = 0.f;
        float lf = 0.f;
        #pragma unroll
        for (int w = 0; w < 4; ++w) {
            const float* cp = comb + ((size_t)(w * ROWS) + tid) * (D + 1);
            #pragma unroll
            for (int dd = 0; dd < D; ++dd) af[dd] += cp[dd];
            lf += cp[D];
        }
        float inv = 1.0f / lf;
        int i = base + tid;
        #pragma unroll
        for (int dd = 0; dd < D; ++dd)
            o[((size_t)bh * D + dd) * N + i] = af[dd] * inv;
    }
}

// ---------- output projection + bias + residual; o layout [bh][d][N] ----------
__global__ void outproj_residual(const float* __restrict__ o, const float* __restrict__ w,
                                 const float* __restrict__ bias, const float* __restrict__ zin,
                                 float* __restrict__ zout, int B, int dim, int inner, int N,
                                 int heads, int d) {
    int t = blockIdx.x * blockDim.x + threadIdx.x;
    int total = B * dim * N;
    if (t >= total) return;
    int n = t % N;
    int c = (t / N) % dim;
    int b = t / (N * dim);
    float val = bias[c] + zin[t];
    const float* wp = w + (size_t)c * inner;
    for (int dd = 0; dd < d; ++dd) {
        #pragma unroll
        for (int hh = 0; hh < 3; ++hh) {
            val += wp[dd * 3 + hh] * o[((size_t)((b * 3 + hh) * d) + dd) * N + n];
        }
    }
    zout[t] = val;
}

// ---------- fused global avg pool + classifier ----------
__global__ void pool_cls(const float* __restrict__ z, const float* __restrict__ w,
                         const float* __restrict__ bias, float* __restrict__ out) {
    __shared__ float p[64];
    int b = blockIdx.x;
    int c = threadIdx.x;  // 64 threads
    const float* zp = z + ((size_t)b * 64 + c) * 64;
    float s = 0.f;
    #pragma unroll
    for (int n = 0; n < 64; ++n) s += zp[n];
    s *= (1.0f / 64.0f);
    p[c] = s;
    out[b * 64 + c] = s;
    __syncthreads();
    if (c < 10) {
        float val = bias[c];
        const float* wp = w + (size_t)c * 64;
        #pragma unroll
        for (int kk = 0; kk < 64; ++kk) val += wp[kk] * p[kk];
        out[2048 + b * 10 + c] = val;
    }
}

extern "C" void kernel_launch(void* const* d_in, const int* in_sizes, int n_in,
                              void* d_out, int out_size, void* d_ws, size_t ws_size,
                              hipStream_t stream) {
    const int B = 32, HEADS = 3, BS = 256;
    const float* x = (const float*)d_in[0];
    float* out = (float*)d_out;

    float* ws = (float*)d_ws;
    float* Z0 = ws;               // 524288 (conv out / attn residual input)
    float* Z1 = Z0 + 524288;      // 524288 (attn out / next conv in)
    float* Q  = Z1 + 524288;      // 491520
    float* K  = Q + 491520;
    float* V  = K + 491520;
    float* O  = V + 491520;

    // ================= layer 1: Cin=1 H64->32, dim=16, inner=15, d=5, N=1024, Hg=32 =================
    {
        const int Cin = 1, dim = 16, Hin = 64, Hout = 32, N = 1024, inner = 15, d = 5;
        const int log2Hg = 5, T = 63 * 63;  // 3969
        conv3x3_s2_relu<<<CDIV(B * dim * Hout * Hout, BS), BS, 0, stream>>>(
            x, (const float*)d_in[1], (const float*)d_in[2], Z0, B, Cin, Hin, dim, Hout);
        qkv_proj<<<CDIV(B * N * 3 * inner, BS), BS, 0, stream>>>(
            Z0, (const float*)d_in[3], (const float*)d_in[4], Q, K, V, B, dim, N, inner, HEADS, d);
        const int IC = 4;  // N / (64*4)
        size_t smem = (size_t)(2 * N * d + T) * 4;  // 56836 B (comb 6144 floats fits inside)
        attn2<5, 4><<<B * HEADS * IC, 256, smem, stream>>>(
            Q, K, V, (const float*)d_in[7], O, N, log2Hg, T, IC, 1.0f / sqrtf(5.0f));
        outproj_residual<<<CDIV(B * dim * N, BS), BS, 0, stream>>>(
            O, (const float*)d_in[5], (const float*)d_in[6], Z0, Z1, B, dim, inner, N, HEADS, d);
    }
    // ================= layer 2: Cin=16 H32->16, dim=32, inner=30, d=10, N=256, Hg=16 =================
    {
        const int Cin = 16, dim = 32, Hin = 32, Hout = 16, N = 256, inner = 30, d = 10;
        const int log2Hg = 4, T = 31 * 31;  // 961
        conv3x3_s2_relu<<<CDIV(B * dim * Hout * Hout, BS), BS, 0, stream>>>(
            Z1, (const float*)d_in[8], (const float*)d_in[9], Z0, B, Cin, Hin, dim, Hout);
        qkv_proj<<<CDIV(B * N * 3 * inner, BS), BS, 0, stream>>>(
            Z0, (const float*)d_in[10], (const float*)d_in[11], Q, K, V, B, dim, N, inner, HEADS, d);
        const int IC = 1;  // N / (64*4)
        size_t smem = (size_t)(4 * 256 * (d + 1)) * 4;  // 45056 B (comb dominates)
        attn2<10, 4><<<B * HEADS * IC, 256, smem, stream>>>(
            Q, K, V, (const float*)d_in[14], O, N, log2Hg, T, IC, 1.0f / sqrtf(10.0f));
        outproj_residual<<<CDIV(B * dim * N, BS), BS, 0, stream>>>(
            O, (const float*)d_in[12], (const float*)d_in[13], Z0, Z1, B, dim, inner, N, HEADS, d);
    }
    // ================= layer 3: Cin=32 H16->8, dim=64, inner=63, d=21, N=64, Hg=8 =================
    {
        const int Cin = 32, dim = 64, Hin = 16, Hout = 8, N = 64, inner = 63, d = 21;
        const int log2Hg = 3, T = 15 * 15;  // 225
        conv3x3_s2_relu<<<CDIV(B * dim * Hout * Hout, BS), BS, 0, stream>>>(
            Z1, (const float*)d_in[15], (const float*)d_in[16], Z0, B, Cin, Hin, dim, Hout);
        qkv_proj<<<CDIV(B * N * 3 * inner, BS), BS, 0, stream>>>(
            Z0, (const float*)d_in[17], (const float*)d_in[18], Q, K, V, B, dim, N, inner, HEADS, d);
        const int IC = 1;  // N / 64
        size_t smem = (size_t)(4 * 64 * (d + 1)) * 4;  // 22528 B (comb dominates)
        attn2<21, 1><<<B * HEADS * IC, 256, smem, stream>>>(
            Q, K, V, (const float*)d_in[21], O, N, log2Hg, T, IC, 1.0f / sqrtf(21.0f));
        outproj_residual<<<CDIV(B * dim * N, BS), BS, 0, stream>>>(
            O, (const float*)d_in[19], (const float*)d_in[20], Z0, Z1, B, dim, inner, N, HEADS, d);
    }
    // ---- fused pool + cls ----
    pool_cls<<<B, 64, 0, stream>>>(Z1, (const float*)d_in[22], (const float*)d_in[23], out);
}